// Round 1
// 545.713 us; speedup vs baseline: 1.0694x; 1.0694x over previous
//
#include <hip/hip_runtime.h>

// ROUND 5: k2 rewrite.
//  - k0: counting sort of paths by length (ascending) -> perm (32 KB in ws).
//  - k2: 256 blocks x 512 thr; block b processes sorted 16-row chunks {b, 511-b}
//    sequentially (balanced ~33 steps total vs 64 chunk-steps unsorted).
//  - Whh AND Wih fragments live in VGPRs (no 139 KB Wh LDS tile, no staging).
//  - x A-fragments loaded per-lane directly from global xt (prefetch t+1),
//    no xb LDS, no staging barrier.
//  - h exchange: double-buffered 16x128 bf16 LDS, XOR-swizzled
//    (col ^ ((row&7)<<3)), ONE barrier per step, conflict-free b128 reads.
// k1/k3 unchanged from round 4.

#define NPATH 8192
#define LMAX  32
#define DIN   256
#define EDIM  128
#define HDIM  128
#define NGRP  1024
#define NTOK  (NPATH * LMAX)   // 262144
#define NCHUNK 512             // 16-row sorted chunks

typedef __attribute__((ext_vector_type(8))) short short8;
typedef __attribute__((ext_vector_type(4))) short s16x4;
typedef __attribute__((ext_vector_type(4))) float f32x4;

__device__ __forceinline__ unsigned short f2bf(float f) {
    unsigned int x = __float_as_uint(f);
    x += 0x7fffu + ((x >> 16) & 1u);   // RNE
    return (unsigned short)(x >> 16);
}
__device__ __forceinline__ float sigmoid_f(float x) {
    return __fdividef(1.f, 1.f + __expf(-x));
}
__device__ __forceinline__ float tanh_f(float x) {
    float ax = fabsf(x);
    float t = __expf(-2.f * ax);
    float r = __fdividef(1.f - t, 1.f + t);
    return copysignf(r, x);
}

// ---------------- K0: counting sort by path length (ascending) --------------
__global__ __launch_bounds__(512) void k0_sort(const int* __restrict__ lens,
                                               int* __restrict__ perm) {
    __shared__ int hist[LMAX];
    __shared__ int offs[LMAX];
    const int tid = threadIdx.x;
    if (tid < LMAX) hist[tid] = 0;
    __syncthreads();
    for (int i = tid; i < NPATH; i += 512) atomicAdd(&hist[lens[i] - 1], 1);
    __syncthreads();
    if (tid == 0) {
        int s = 0;
        for (int b = 0; b < LMAX; ++b) { offs[b] = s; s += hist[b]; }
    }
    __syncthreads();
    for (int i = tid; i < NPATH; i += 512) {
        int p = atomicAdd(&offs[lens[i] - 1], 1);
        perm[p] = i;
    }
}

// ---------------- K1: projection GEMM + LayerNorm + tanh -> x~ (bf16 ws) ----
#define K1_ROWS 128
#define K1_PAD  264   // 256 + 8 elems: 528B row stride, 16B aligned
__global__ __launch_bounds__(512) void k1_proj(
    const float* __restrict__ inp, const float* __restrict__ Win,
    const float* __restrict__ gam, const float* __restrict__ bet,
    unsigned short* __restrict__ xt)
{
    __shared__ short As[K1_ROWS * K1_PAD];  // 67584 B
    __shared__ short Bs[EDIM * K1_PAD];     // 67584 B
    const int tid = threadIdx.x;
    const long m0 = (long)blockIdx.x * K1_ROWS;

    #pragma unroll
    for (int i = 0; i < 16; ++i) {          // W_in: 128x256 fp32 = 8192 float4
        int chunk = i * 512 + tid;
        int row = chunk >> 6, c4 = chunk & 63;
        float4 v = *(const float4*)&Win[row * DIN + c4 * 4];
        s16x4 s = { (short)f2bf(v.x), (short)f2bf(v.y), (short)f2bf(v.z), (short)f2bf(v.w) };
        *(s16x4*)&Bs[row * K1_PAD + c4 * 4] = s;
    }
    #pragma unroll
    for (int i = 0; i < 16; ++i) {          // A-tile: 128x256 fp32
        int chunk = i * 512 + tid;
        int row = chunk >> 6, c4 = chunk & 63;
        float4 v = *(const float4*)&inp[(m0 + row) * DIN + c4 * 4];
        s16x4 s = { (short)f2bf(v.x), (short)f2bf(v.y), (short)f2bf(v.z), (short)f2bf(v.w) };
        *(s16x4*)&As[row * K1_PAD + c4 * 4] = s;
    }
    __syncthreads();

    const int w = tid >> 6, lane = tid & 63, q = lane >> 4, c = lane & 15;
    const f32x4 fzero = {0.f, 0.f, 0.f, 0.f};
    f32x4 acc[8];
    #pragma unroll
    for (int nt = 0; nt < 8; ++nt) acc[nt] = fzero;

    const short* arow = &As[(w * 16 + c) * K1_PAD + q * 8];
    const short* brow = &Bs[c * K1_PAD + q * 8];
    #pragma unroll
    for (int ks = 0; ks < 8; ++ks) {
        short8 a = *(const short8*)(arow + ks * 32);
        #pragma unroll
        for (int nt = 0; nt < 8; ++nt) {
            short8 b = *(const short8*)(brow + nt * 16 * K1_PAD + ks * 32);
            acc[nt] = __builtin_amdgcn_mfma_f32_16x16x32_bf16(a, b, acc[nt], 0, 0, 0);
        }
    }

    // LayerNorm per row (row = m0 + 16w + 4q + r), cols = 16*nt + c
    float gr[8], br[8];
    #pragma unroll
    for (int nt = 0; nt < 8; ++nt) { int col = nt * 16 + c; gr[nt] = gam[col]; br[nt] = bet[col]; }
    #pragma unroll
    for (int r = 0; r < 4; ++r) {
        float s = 0.f, ss = 0.f;
        #pragma unroll
        for (int nt = 0; nt < 8; ++nt) { float v = acc[nt][r]; s += v; ss += v * v; }
        #pragma unroll
        for (int m = 1; m < 16; m <<= 1) { s += __shfl_xor(s, m, 64); ss += __shfl_xor(ss, m, 64); }
        float mu = s * (1.f / 128.f);
        float var = ss * (1.f / 128.f) - mu * mu;
        float rstd = rsqrtf(var + 1e-5f);
        unsigned short* orow = &xt[(m0 + w * 16 + q * 4 + r) * EDIM];
        #pragma unroll
        for (int nt = 0; nt < 8; ++nt) {
            float v = (acc[nt][r] - mu) * rstd * gr[nt] + br[nt];
            orow[nt * 16 + c] = f2bf(tanh_f(v));
        }
    }
}

// ---------------- K2: LSTM, length-sorted paired 16-row chunks ---------------
// 8 waves: wave w owns gate-cols g*128 + w*16 + c. A rows = c (16 paths).
// Weights (Wih+Whh bf16 fragments) in VGPRs. h exchanged via swizzled LDS.
__global__ __launch_bounds__(512, 2) void k2_lstm(
    const unsigned short* __restrict__ xt,
    const float* __restrict__ Wih, const float* __restrict__ Whh,
    const float* __restrict__ bih, const float* __restrict__ bhh,
    const int* __restrict__ lens, const int* __restrict__ perm,
    float* __restrict__ h_last)
{
    __shared__ unsigned short hb[2][16 * 128];   // 8192 B, XOR-swizzled rows
    __shared__ int pemb[16];
    __shared__ int lenb[16];
    const int tid = threadIdx.x;
    const int w = tid >> 6, lane = tid & 63, q = lane >> 4, c = lane & 15;
    const int xr = (c & 7) << 3;   // short-index XOR key for A-frag rows (row==c)

    // step-invariant weight fragments, fp32->bf16 once into VGPRs
    short8 wf[4][4], whf[4][4];
    float bs[4];
    #pragma unroll
    for (int g = 0; g < 4; ++g) {
        const int j = g * 128 + w * 16 + c;
        bs[g] = bih[j] + bhh[j];
        const float* pi = Wih + (long)j * EDIM + q * 8;
        const float* ph = Whh + (long)j * HDIM + q * 8;
        #pragma unroll
        for (int ks = 0; ks < 4; ++ks) {
            float4 a0 = *(const float4*)(pi + ks * 32);
            float4 a1 = *(const float4*)(pi + ks * 32 + 4);
            short8 s;
            s[0] = (short)f2bf(a0.x); s[1] = (short)f2bf(a0.y);
            s[2] = (short)f2bf(a0.z); s[3] = (short)f2bf(a0.w);
            s[4] = (short)f2bf(a1.x); s[5] = (short)f2bf(a1.y);
            s[6] = (short)f2bf(a1.z); s[7] = (short)f2bf(a1.w);
            wf[g][ks] = s;
            float4 b0 = *(const float4*)(ph + ks * 32);
            float4 b1 = *(const float4*)(ph + ks * 32 + 4);
            short8 u;
            u[0] = (short)f2bf(b0.x); u[1] = (short)f2bf(b0.y);
            u[2] = (short)f2bf(b0.z); u[3] = (short)f2bf(b0.w);
            u[4] = (short)f2bf(b1.x); u[5] = (short)f2bf(b1.y);
            u[6] = (short)f2bf(b1.z); u[7] = (short)f2bf(b1.w);
            whf[g][ks] = u;
        }
    }

    #pragma unroll
    for (int half = 0; half < 2; ++half) {
        // balanced pairing: block b runs sorted chunk b then chunk 511-b
        const int cid = half ? (NCHUNK - 1 - (int)blockIdx.x) : (int)blockIdx.x;
        const int r0 = cid * 16;
        if (tid < 16) { int p = perm[r0 + tid]; pemb[tid] = p; lenb[tid] = lens[p]; }
        { s16x4 z = {0, 0, 0, 0}; *(s16x4*)&hb[0][tid * 4] = z; }  // h(0) = 0
        __syncthreads();

        int steps = 1;
        #pragma unroll
        for (int i = 0; i < 16; ++i) steps = (lenb[i] > steps) ? lenb[i] : steps;
        int lenr[4];
        #pragma unroll
        for (int r = 0; r < 4; ++r) lenr[r] = lenb[q * 4 + r];
        const unsigned short* xrow = xt + (long)pemb[c] * (LMAX * EDIM) + q * 8;

        float c_reg[4] = {0.f, 0.f, 0.f, 0.f};
        float h_reg[4] = {0.f, 0.f, 0.f, 0.f};
        short8 xf[4];                       // A-frags of x for current step
        #pragma unroll
        for (int ks = 0; ks < 4; ++ks) xf[ks] = *(const short8*)(xrow + ks * 32);

        int cur = 0;
        for (int t = 0; t < steps; ++t) {
            f32x4 acc[4];
            #pragma unroll
            for (int g = 0; g < 4; ++g) {   // bias pre-loaded into accumulator
                f32x4 a = {bs[g], bs[g], bs[g], bs[g]};
                acc[g] = a;
            }
            if (t) {                        // recurrent part (h(0)=0: skip)
                short8 ha[4];
                #pragma unroll
                for (int ks = 0; ks < 4; ++ks)
                    ha[ks] = *(const short8*)&hb[cur][c * 128 + ((q * 8 + ks * 32) ^ xr)];
                #pragma unroll
                for (int ks = 0; ks < 4; ++ks)
                    #pragma unroll
                    for (int g = 0; g < 4; ++g)
                        acc[g] = __builtin_amdgcn_mfma_f32_16x16x32_bf16(ha[ks], whf[g][ks], acc[g], 0, 0, 0);
            }
            #pragma unroll
            for (int ks = 0; ks < 4; ++ks)  // input part (xf prefetched)
                #pragma unroll
                for (int g = 0; g < 4; ++g)
                    acc[g] = __builtin_amdgcn_mfma_f32_16x16x32_bf16(xf[ks], wf[g][ks], acc[g], 0, 0, 0);
            {   // prefetch x A-frags for t+1 (hidden under activations+barrier)
                const int tn = (t + 1 < steps) ? (t + 1) : t;
                const unsigned short* xp = xrow + (long)tn * EDIM;
                #pragma unroll
                for (int ks = 0; ks < 4; ++ks) xf[ks] = *(const short8*)(xp + ks * 32);
            }
            const int nxt = cur ^ 1;
            #pragma unroll
            for (int r = 0; r < 4; ++r) {   // acc[g][r]: row q*4+r, gate g
                float cn = sigmoid_f(acc[1][r]) * c_reg[r]
                         + sigmoid_f(acc[0][r]) * tanh_f(acc[2][r]);
                float hn = sigmoid_f(acc[3][r]) * tanh_f(cn);
                if (t < lenr[r]) { c_reg[r] = cn; h_reg[r] = hn; }
                const int row = q * 4 + r;
                hb[nxt][row * 128 + ((w * 16 + c) ^ ((row & 7) << 3))] = f2bf(h_reg[r]);
            }
            __syncthreads();                // single barrier per step (dbuf)
            cur = nxt;
        }
        #pragma unroll
        for (int r = 0; r < 4; ++r)
            h_last[(long)pemb[q * 4 + r] * HDIM + w * 16 + c] = h_reg[r];
        if (half == 0) __syncthreads();     // pemb/lenb/hb reused by 2nd chunk
    }
}

// ---------------- K3: segmented softmax attention + output GEMMs (fp32 out) -
__global__ __launch_bounds__(64) void k3_attn(
    const float* __restrict__ h_last, const int* __restrict__ seg,
    const float* __restrict__ attn, const float* __restrict__ Wout,
    const float* __restrict__ Wcls, float* __restrict__ out)
{
    __shared__ float code_s[128];
    const int g = blockIdx.x, l = threadIdx.x;

    int lo, hi;
    { int a = 0, b = NPATH; while (a < b) { int m = (a + b) >> 1; if (seg[m] < g) a = m + 1; else b = m; } lo = a; }
    { int a = lo, b = NPATH; while (a < b) { int m = (a + b) >> 1; if (seg[m] < g + 1) a = m + 1; else b = m; } hi = a; }

    float a0 = attn[l], a1 = attn[l + 64];
    float mrun = -1e30f, Z = 0.f;
    for (int n = lo; n < hi; ++n) {        // online softmax stats
        const float* hr = &h_last[(long)n * HDIM];
        float v = hr[l] * a0 + hr[l + 64] * a1;
        #pragma unroll
        for (int m = 1; m < 64; m <<= 1) v += __shfl_xor(v, m, 64);
        float nm = fmaxf(mrun, v);
        Z = Z * __expf(mrun - nm) + __expf(v - nm);
        mrun = nm;
    }
    float w0 = 0.f, w1 = 0.f;
    for (int n = lo; n < hi; ++n) {        // weighted sum
        const float* hr = &h_last[(long)n * HDIM];
        float v = hr[l] * a0 + hr[l + 64] * a1;
        #pragma unroll
        for (int m = 1; m < 64; m <<= 1) v += __shfl_xor(v, m, 64);
        float at = __expf(v - mrun) / Z;
        w0 += at * hr[l]; w1 += at * hr[l + 64];
    }
    float inv_cnt = (hi > lo) ? 1.f / (float)(hi - lo) : 0.f;
    code_s[l] = w0 * inv_cnt; code_s[l + 64] = w1 * inv_cnt;
    __syncthreads();

    float cv0 = 0.f, cv1 = 0.f;            // code @ W_out.T
    for (int k = 0; k < 128; ++k) {
        float ck = code_s[k];
        cv0 += ck * Wout[l * 128 + k];
        cv1 += ck * Wout[(l + 64) * 128 + k];
    }
    out[2048 + g * 128 + l]      = cv0;
    out[2048 + g * 128 + l + 64] = cv1;

    float p0 = cv0 * Wcls[l] + cv1 * Wcls[l + 64];          // cv @ W_cls.T
    float p1 = cv0 * Wcls[128 + l] + cv1 * Wcls[128 + l + 64];
    #pragma unroll
    for (int m = 1; m < 64; m <<= 1) { p0 += __shfl_xor(p0, m, 64); p1 += __shfl_xor(p1, m, 64); }
    if (l == 0) { out[g * 2 + 0] = p0; out[g * 2 + 1] = p1; }
    if (g == 0) { out[133120 + l] = attn[l]; out[133120 + 64 + l] = attn[l + 64]; }
}

extern "C" void kernel_launch(void* const* d_in, const int* in_sizes, int n_in,
                              void* d_out, int out_size, void* d_ws, size_t ws_size,
                              hipStream_t stream) {
    const float* inp  = (const float*)d_in[0];
    const int*   lens = (const int*)d_in[1];
    const int*   seg  = (const int*)d_in[2];
    const float* Win  = (const float*)d_in[3];
    const float* gam  = (const float*)d_in[4];
    const float* bet  = (const float*)d_in[5];
    const float* Wih  = (const float*)d_in[6];
    const float* Whh  = (const float*)d_in[7];
    const float* bih  = (const float*)d_in[8];
    const float* bhh  = (const float*)d_in[9];
    const float* attn = (const float*)d_in[10];
    const float* Wout = (const float*)d_in[11];
    const float* Wcls = (const float*)d_in[12];

    unsigned short* xt = (unsigned short*)d_ws;                               // 64 MB bf16 x~
    float* h_last = (float*)((char*)d_ws + (size_t)NTOK * EDIM * 2);          // 4 MB f32
    int* perm = (int*)((char*)d_ws + (size_t)NTOK * EDIM * 2
                                   + (size_t)NPATH * HDIM * 4);               // 32 KB

    hipLaunchKernelGGL(k0_sort, dim3(1), dim3(512), 0, stream, lens, perm);
    hipLaunchKernelGGL(k1_proj, dim3(NTOK / K1_ROWS), dim3(512), 0, stream, inp, Win, gam, bet, xt);
    hipLaunchKernelGGL(k2_lstm, dim3(NCHUNK / 2), dim3(512), 0, stream,
                       xt, Wih, Whh, bih, bhh, lens, perm, h_last);
    hipLaunchKernelGGL(k3_attn, dim3(NGRP), dim3(64), 0, stream, h_last, seg, attn, Wout, Wcls,
                       (float*)d_out);
}

// Round 3
// 529.879 us; speedup vs baseline: 1.1014x; 1.0299x over previous
//
#include <hip/hip_runtime.h>

// ROUND 7: identical to round 6 (bench infra failed; kernel never ran).
// k2 register-pressure fix (spill hypothesis):
//  - Wih fragments move VGPR -> LDS (128 KB, XOR-swizzled [j][k ^ ((j&7)<<3)],
//    conflict-free ds_read_b128; same swizzle family as hb).
//  - Whh stays in VGPRs (feeds the critical post-barrier recurrent MFMAs).
//  - VGPR demand ~215 -> ~150: eliminates any chance of scratch spills under
//    the launch_bounds(512,2) 256-reg cap.
// k0/k1/k3 unchanged.

#define NPATH 8192
#define LMAX  32
#define DIN   256
#define EDIM  128
#define HDIM  128
#define NGRP  1024
#define NTOK  (NPATH * LMAX)   // 262144
#define NCHUNK 512             // 16-row sorted chunks

typedef __attribute__((ext_vector_type(8))) short short8;
typedef __attribute__((ext_vector_type(4))) short s16x4;
typedef __attribute__((ext_vector_type(4))) float f32x4;

__device__ __forceinline__ unsigned short f2bf(float f) {
    unsigned int x = __float_as_uint(f);
    x += 0x7fffu + ((x >> 16) & 1u);   // RNE
    return (unsigned short)(x >> 16);
}
__device__ __forceinline__ float sigmoid_f(float x) {
    return __fdividef(1.f, 1.f + __expf(-x));
}
__device__ __forceinline__ float tanh_f(float x) {
    float ax = fabsf(x);
    float t = __expf(-2.f * ax);
    float r = __fdividef(1.f - t, 1.f + t);
    return copysignf(r, x);
}

// ---------------- K0: counting sort by path length (ascending) --------------
__global__ __launch_bounds__(512) void k0_sort(const int* __restrict__ lens,
                                               int* __restrict__ perm) {
    __shared__ int hist[LMAX];
    __shared__ int offs[LMAX];
    const int tid = threadIdx.x;
    if (tid < LMAX) hist[tid] = 0;
    __syncthreads();
    for (int i = tid; i < NPATH; i += 512) atomicAdd(&hist[lens[i] - 1], 1);
    __syncthreads();
    if (tid == 0) {
        int s = 0;
        for (int b = 0; b < LMAX; ++b) { offs[b] = s; s += hist[b]; }
    }
    __syncthreads();
    for (int i = tid; i < NPATH; i += 512) {
        int p = atomicAdd(&offs[lens[i] - 1], 1);
        perm[p] = i;
    }
}

// ---------------- K1: projection GEMM + LayerNorm + tanh -> x~ (bf16 ws) ----
#define K1_ROWS 128
#define K1_PAD  264   // 256 + 8 elems: 528B row stride, 16B aligned
__global__ __launch_bounds__(512) void k1_proj(
    const float* __restrict__ inp, const float* __restrict__ Win,
    const float* __restrict__ gam, const float* __restrict__ bet,
    unsigned short* __restrict__ xt)
{
    __shared__ short As[K1_ROWS * K1_PAD];  // 67584 B
    __shared__ short Bs[EDIM * K1_PAD];     // 67584 B
    const int tid = threadIdx.x;
    const long m0 = (long)blockIdx.x * K1_ROWS;

    #pragma unroll
    for (int i = 0; i < 16; ++i) {          // W_in: 128x256 fp32 = 8192 float4
        int chunk = i * 512 + tid;
        int row = chunk >> 6, c4 = chunk & 63;
        float4 v = *(const float4*)&Win[row * DIN + c4 * 4];
        s16x4 s = { (short)f2bf(v.x), (short)f2bf(v.y), (short)f2bf(v.z), (short)f2bf(v.w) };
        *(s16x4*)&Bs[row * K1_PAD + c4 * 4] = s;
    }
    #pragma unroll
    for (int i = 0; i < 16; ++i) {          // A-tile: 128x256 fp32
        int chunk = i * 512 + tid;
        int row = chunk >> 6, c4 = chunk & 63;
        float4 v = *(const float4*)&inp[(m0 + row) * DIN + c4 * 4];
        s16x4 s = { (short)f2bf(v.x), (short)f2bf(v.y), (short)f2bf(v.z), (short)f2bf(v.w) };
        *(s16x4*)&As[row * K1_PAD + c4 * 4] = s;
    }
    __syncthreads();

    const int w = tid >> 6, lane = tid & 63, q = lane >> 4, c = lane & 15;
    const f32x4 fzero = {0.f, 0.f, 0.f, 0.f};
    f32x4 acc[8];
    #pragma unroll
    for (int nt = 0; nt < 8; ++nt) acc[nt] = fzero;

    const short* arow = &As[(w * 16 + c) * K1_PAD + q * 8];
    const short* brow = &Bs[c * K1_PAD + q * 8];
    #pragma unroll
    for (int ks = 0; ks < 8; ++ks) {
        short8 a = *(const short8*)(arow + ks * 32);
        #pragma unroll
        for (int nt = 0; nt < 8; ++nt) {
            short8 b = *(const short8*)(brow + nt * 16 * K1_PAD + ks * 32);
            acc[nt] = __builtin_amdgcn_mfma_f32_16x16x32_bf16(a, b, acc[nt], 0, 0, 0);
        }
    }

    // LayerNorm per row (row = m0 + 16w + 4q + r), cols = 16*nt + c
    float gr[8], br[8];
    #pragma unroll
    for (int nt = 0; nt < 8; ++nt) { int col = nt * 16 + c; gr[nt] = gam[col]; br[nt] = bet[col]; }
    #pragma unroll
    for (int r = 0; r < 4; ++r) {
        float s = 0.f, ss = 0.f;
        #pragma unroll
        for (int nt = 0; nt < 8; ++nt) { float v = acc[nt][r]; s += v; ss += v * v; }
        #pragma unroll
        for (int m = 1; m < 16; m <<= 1) { s += __shfl_xor(s, m, 64); ss += __shfl_xor(ss, m, 64); }
        float mu = s * (1.f / 128.f);
        float var = ss * (1.f / 128.f) - mu * mu;
        float rstd = rsqrtf(var + 1e-5f);
        unsigned short* orow = &xt[(m0 + w * 16 + q * 4 + r) * EDIM];
        #pragma unroll
        for (int nt = 0; nt < 8; ++nt) {
            float v = (acc[nt][r] - mu) * rstd * gr[nt] + br[nt];
            orow[nt * 16 + c] = f2bf(tanh_f(v));
        }
    }
}

// ---------------- K2: LSTM, length-sorted paired 16-row chunks ---------------
// 8 waves: wave w owns gate-cols g*128 + w*16 + c. A rows = c (16 paths).
// Whh fragments in VGPRs; Wih in swizzled LDS (read per step, conflict-free);
// h exchanged via swizzled double-buffered LDS, one barrier per step.
__global__ __launch_bounds__(512, 2) void k2_lstm(
    const unsigned short* __restrict__ xt,
    const float* __restrict__ Wih, const float* __restrict__ Whh,
    const float* __restrict__ bih, const float* __restrict__ bhh,
    const int* __restrict__ lens, const int* __restrict__ perm,
    float* __restrict__ h_last)
{
    __shared__ unsigned short wih_s[512 * 128];  // 131072 B, swizzled rows
    __shared__ unsigned short hb[2][16 * 128];   // 8192 B, swizzled rows
    __shared__ int pemb[16];
    __shared__ int lenb[16];
    const int tid = threadIdx.x;
    const int w = tid >> 6, lane = tid & 63, q = lane >> 4, c = lane & 15;
    const int xr = (c & 7) << 3;   // short-index XOR key for A/B rows (row==c)

    // ---- stage Wih -> LDS as bf16, row-swizzled: [j][k ^ ((j&7)<<3)] ----
    #pragma unroll
    for (int i = 0; i < 32; ++i) {           // 512x128 fp32 = 16384 float4
        int chunk = i * 512 + tid;
        int j = chunk >> 5, c4 = chunk & 31;
        float4 v = *(const float4*)&Wih[j * EDIM + c4 * 4];
        s16x4 s = { (short)f2bf(v.x), (short)f2bf(v.y), (short)f2bf(v.z), (short)f2bf(v.w) };
        *(s16x4*)&wih_s[j * 128 + ((c4 * 4) ^ ((j & 7) << 3))] = s;
    }

    // ---- step-invariant Whh fragments + fused bias, fp32->bf16 into VGPRs ----
    short8 whf[4][4];
    float bs[4];
    #pragma unroll
    for (int g = 0; g < 4; ++g) {
        const int j = g * 128 + w * 16 + c;
        bs[g] = bih[j] + bhh[j];
        const float* ph = Whh + (long)j * HDIM + q * 8;
        #pragma unroll
        for (int ks = 0; ks < 4; ++ks) {
            float4 b0 = *(const float4*)(ph + ks * 32);
            float4 b1 = *(const float4*)(ph + ks * 32 + 4);
            short8 u;
            u[0] = (short)f2bf(b0.x); u[1] = (short)f2bf(b0.y);
            u[2] = (short)f2bf(b0.z); u[3] = (short)f2bf(b0.w);
            u[4] = (short)f2bf(b1.x); u[5] = (short)f2bf(b1.y);
            u[6] = (short)f2bf(b1.z); u[7] = (short)f2bf(b1.w);
            whf[g][ks] = u;
        }
    }

    // step-invariant swizzled k-offsets (shorts) shared by hb reads & wih reads
    int koff[4];
    #pragma unroll
    for (int ks = 0; ks < 4; ++ks) koff[ks] = (q * 8 + ks * 32) ^ xr;
    const unsigned short* wbase[4];
    #pragma unroll
    for (int g = 0; g < 4; ++g) wbase[g] = &wih_s[(g * 128 + w * 16 + c) * 128];

    for (int half = 0; half < 2; ++half) {
        // balanced pairing: block b runs sorted chunk b then chunk 511-b
        const int cid = half ? (NCHUNK - 1 - (int)blockIdx.x) : (int)blockIdx.x;
        const int r0 = cid * 16;
        if (tid < 16) { int p = perm[r0 + tid]; pemb[tid] = p; lenb[tid] = lens[p]; }
        { s16x4 z = {0, 0, 0, 0}; *(s16x4*)&hb[0][tid * 4] = z; }  // h(0) = 0
        __syncthreads();

        int steps = 1;
        #pragma unroll
        for (int i = 0; i < 16; ++i) steps = (lenb[i] > steps) ? lenb[i] : steps;
        int lenr[4];
        #pragma unroll
        for (int r = 0; r < 4; ++r) lenr[r] = lenb[q * 4 + r];
        const unsigned short* xrow = xt + (long)pemb[c] * (LMAX * EDIM) + q * 8;

        float c_reg[4] = {0.f, 0.f, 0.f, 0.f};
        float h_reg[4] = {0.f, 0.f, 0.f, 0.f};
        short8 xf[4];                       // A-frags of x for current step
        #pragma unroll
        for (int ks = 0; ks < 4; ++ks) xf[ks] = *(const short8*)(xrow + ks * 32);

        int cur = 0;
        for (int t = 0; t < steps; ++t) {
            f32x4 acc[4];
            #pragma unroll
            for (int g = 0; g < 4; ++g) {   // bias pre-loaded into accumulator
                f32x4 a = {bs[g], bs[g], bs[g], bs[g]};
                acc[g] = a;
            }
            if (t) {                        // recurrent part (h(0)=0: skip)
                short8 ha[4];
                #pragma unroll
                for (int ks = 0; ks < 4; ++ks)
                    ha[ks] = *(const short8*)&hb[cur][c * 128 + koff[ks]];
                #pragma unroll
                for (int ks = 0; ks < 4; ++ks)
                    #pragma unroll
                    for (int g = 0; g < 4; ++g)
                        acc[g] = __builtin_amdgcn_mfma_f32_16x16x32_bf16(ha[ks], whf[g][ks], acc[g], 0, 0, 0);
            }
            #pragma unroll
            for (int ks = 0; ks < 4; ++ks)  // input part: B-frags streamed from LDS
                #pragma unroll
                for (int g = 0; g < 4; ++g) {
                    short8 b = *(const short8*)(wbase[g] + koff[ks]);
                    acc[g] = __builtin_amdgcn_mfma_f32_16x16x32_bf16(xf[ks], b, acc[g], 0, 0, 0);
                }
            {   // prefetch x A-frags for t+1 (hidden under activations+barrier)
                const int tn = (t + 1 < steps) ? (t + 1) : t;
                const unsigned short* xp = xrow + (long)tn * EDIM;
                #pragma unroll
                for (int ks = 0; ks < 4; ++ks) xf[ks] = *(const short8*)(xp + ks * 32);
            }
            const int nxt = cur ^ 1;
            #pragma unroll
            for (int r = 0; r < 4; ++r) {   // acc[g][r]: row q*4+r, gate g
                float cn = sigmoid_f(acc[1][r]) * c_reg[r]
                         + sigmoid_f(acc[0][r]) * tanh_f(acc[2][r]);
                float hn = sigmoid_f(acc[3][r]) * tanh_f(cn);
                if (t < lenr[r]) { c_reg[r] = cn; h_reg[r] = hn; }
                const int row = q * 4 + r;
                hb[nxt][row * 128 + ((w * 16 + c) ^ ((row & 7) << 3))] = f2bf(h_reg[r]);
            }
            __syncthreads();                // single barrier per step (dbuf)
            cur = nxt;
        }
        #pragma unroll
        for (int r = 0; r < 4; ++r)
            h_last[(long)pemb[q * 4 + r] * HDIM + w * 16 + c] = h_reg[r];
        if (half == 0) __syncthreads();     // pemb/lenb/hb reused by 2nd chunk
    }
}

// ---------------- K3: segmented softmax attention + output GEMMs (fp32 out) -
__global__ __launch_bounds__(64) void k3_attn(
    const float* __restrict__ h_last, const int* __restrict__ seg,
    const float* __restrict__ attn, const float* __restrict__ Wout,
    const float* __restrict__ Wcls, float* __restrict__ out)
{
    __shared__ float code_s[128];
    const int g = blockIdx.x, l = threadIdx.x;

    int lo, hi;
    { int a = 0, b = NPATH; while (a < b) { int m = (a + b) >> 1; if (seg[m] < g) a = m + 1; else b = m; } lo = a; }
    { int a = lo, b = NPATH; while (a < b) { int m = (a + b) >> 1; if (seg[m] < g + 1) a = m + 1; else b = m; } hi = a; }

    float a0 = attn[l], a1 = attn[l + 64];
    float mrun = -1e30f, Z = 0.f;
    for (int n = lo; n < hi; ++n) {        // online softmax stats
        const float* hr = &h_last[(long)n * HDIM];
        float v = hr[l] * a0 + hr[l + 64] * a1;
        #pragma unroll
        for (int m = 1; m < 64; m <<= 1) v += __shfl_xor(v, m, 64);
        float nm = fmaxf(mrun, v);
        Z = Z * __expf(mrun - nm) + __expf(v - nm);
        mrun = nm;
    }
    float w0 = 0.f, w1 = 0.f;
    for (int n = lo; n < hi; ++n) {        // weighted sum
        const float* hr = &h_last[(long)n * HDIM];
        float v = hr[l] * a0 + hr[l + 64] * a1;
        #pragma unroll
        for (int m = 1; m < 64; m <<= 1) v += __shfl_xor(v, m, 64);
        float at = __expf(v - mrun) / Z;
        w0 += at * hr[l]; w1 += at * hr[l + 64];
    }
    float inv_cnt = (hi > lo) ? 1.f / (float)(hi - lo) : 0.f;
    code_s[l] = w0 * inv_cnt; code_s[l + 64] = w1 * inv_cnt;
    __syncthreads();

    float cv0 = 0.f, cv1 = 0.f;            // code @ W_out.T
    for (int k = 0; k < 128; ++k) {
        float ck = code_s[k];
        cv0 += ck * Wout[l * 128 + k];
        cv1 += ck * Wout[(l + 64) * 128 + k];
    }
    out[2048 + g * 128 + l]      = cv0;
    out[2048 + g * 128 + l + 64] = cv1;

    float p0 = cv0 * Wcls[l] + cv1 * Wcls[l + 64];          // cv @ W_cls.T
    float p1 = cv0 * Wcls[128 + l] + cv1 * Wcls[128 + l + 64];
    #pragma unroll
    for (int m = 1; m < 64; m <<= 1) { p0 += __shfl_xor(p0, m, 64); p1 += __shfl_xor(p1, m, 64); }
    if (l == 0) { out[g * 2 + 0] = p0; out[g * 2 + 1] = p1; }
    if (g == 0) { out[133120 + l] = attn[l]; out[133120 + 64 + l] = attn[l + 64]; }
}

extern "C" void kernel_launch(void* const* d_in, const int* in_sizes, int n_in,
                              void* d_out, int out_size, void* d_ws, size_t ws_size,
                              hipStream_t stream) {
    const float* inp  = (const float*)d_in[0];
    const int*   lens = (const int*)d_in[1];
    const int*   seg  = (const int*)d_in[2];
    const float* Win  = (const float*)d_in[3];
    const float* gam  = (const float*)d_in[4];
    const float* bet  = (const float*)d_in[5];
    const float* Wih  = (const float*)d_in[6];
    const float* Whh  = (const float*)d_in[7];
    const float* bih  = (const float*)d_in[8];
    const float* bhh  = (const float*)d_in[9];
    const float* attn = (const float*)d_in[10];
    const float* Wout = (const float*)d_in[11];
    const float* Wcls = (const float*)d_in[12];

    unsigned short* xt = (unsigned short*)d_ws;                               // 64 MB bf16 x~
    float* h_last = (float*)((char*)d_ws + (size_t)NTOK * EDIM * 2);          // 4 MB f32
    int* perm = (int*)((char*)d_ws + (size_t)NTOK * EDIM * 2
                                   + (size_t)NPATH * HDIM * 4);               // 32 KB

    hipLaunchKernelGGL(k0_sort, dim3(1), dim3(512), 0, stream, lens, perm);
    hipLaunchKernelGGL(k1_proj, dim3(NTOK / K1_ROWS), dim3(512), 0, stream, inp, Win, gam, bet, xt);
    hipLaunchKernelGGL(k2_lstm, dim3(NCHUNK / 2), dim3(512), 0, stream,
                       xt, Wih, Whh, bih, bhh, lens, perm, h_last);
    hipLaunchKernelGGL(k3_attn, dim3(NGRP), dim3(64), 0, stream, h_last, seg, attn, Wout, Wcls,
                       (float*)d_out);
}